// Round 1
// baseline (325.952 us; speedup 1.0000x reference)
//
#include <hip/hip_runtime.h>

typedef short bf16x8_t __attribute__((ext_vector_type(8)));
typedef float f32x4_t  __attribute__((ext_vector_type(4)));

#define MFMA16(a,b,c) __builtin_amdgcn_mfma_f32_16x16x32_bf16(a,b,c,0,0,0)

__device__ __forceinline__ unsigned short f2b(float x){
  unsigned u = __float_as_uint(x);
  u += 0x7fffu + ((u >> 16) & 1u);
  return (unsigned short)(u >> 16);
}

// ---------------- prep: Wv -> bf16 rowmajor [e][d]; WkT[d][e] = bf16(key_w[e][d]) ----------------
__global__ void prep_w(const float* __restrict__ kw, const float* __restrict__ vw,
                       unsigned short* __restrict__ wvb, unsigned short* __restrict__ wktb){
  int i = blockIdx.x * 256 + threadIdx.x;          // 0..65535
  wvb[i] = f2b(vw[i]);
  int d = i >> 8, e = i & 255;
  wktb[i] = f2b(kw[e * 256 + d]);
}

// ---------------- qs[b*32+q][e] = (queries[q,e] + context[b]@cond_w[q*256+e] + cond_b)*scale*inv_t ----------------
__global__ __launch_bounds__(256) void calc_qs(
    const float* __restrict__ context, const float* __restrict__ queries,
    const float* __restrict__ logt, const float* __restrict__ condw,
    const float* __restrict__ condb, unsigned short* __restrict__ qs){
  __shared__ float ctx_l[64 * 64];
  int tid = threadIdx.x;
  int q   = blockIdx.x & 31;
  int b0  = (blockIdx.x >> 5) * 64;
  int qd  = q * 256 + tid;
  float4 cw[16];
  #pragma unroll
  for (int j = 0; j < 16; ++j) cw[j] = *(const float4*)(condw + (size_t)qd * 64 + 4 * j);
  float qbias = queries[qd] + condb[qd];
  float sc = 0.0625f * __expf(-logt[q >> 2]);      // scale * inv_temperature
  #pragma unroll
  for (int j = 0; j < 16; ++j){
    int f = j * 256 + tid;
    ctx_l[f] = context[(size_t)b0 * 64 + f];
  }
  __syncthreads();
  for (int b = 0; b < 64; ++b){
    const float4* cl = (const float4*)(ctx_l + b * 64);
    float acc = 0.f;
    #pragma unroll
    for (int j = 0; j < 16; ++j){
      float4 cv = cl[j]; float4 w4 = cw[j];
      acc += cv.x * w4.x + cv.y * w4.y + cv.z * w4.z + cv.w * w4.w;
    }
    qs[((size_t)(b0 + b) * 32 + q) * 256 + tid] = f2b((qbias + acc) * sc);
  }
}

// ---------------- qkp[row][d] = sum_e qs[row][e] * WkT[d][e]   (row = b*32+q) ----------------
__global__ __launch_bounds__(256) void calc_qkp(
    const unsigned short* __restrict__ qs, const unsigned short* __restrict__ wkt,
    unsigned short* __restrict__ qkp){
  __shared__ unsigned short at[64 * 256];
  int tid = threadIdx.x, w = tid >> 6, l = tid & 63, h = l >> 4, c = l & 15;
  size_t r0 = (size_t)blockIdx.x * 64;
  #pragma unroll
  for (int j = 0; j < 8; ++j){
    int f = j * 256 + tid;
    int row = f >> 5, col = (f & 31) * 8;
    bf16x8_t v = *(const bf16x8_t*)(qs + (r0 + row) * 256 + col);
    *(bf16x8_t*)&at[row * 256 + (col ^ ((row & 7) << 3))] = v;
  }
  __syncthreads();
  f32x4_t zero4 = {0.f, 0.f, 0.f, 0.f};
  f32x4_t acc[4][4];
  #pragma unroll
  for (int mt = 0; mt < 4; ++mt)
    #pragma unroll
    for (int nt = 0; nt < 4; ++nt) acc[mt][nt] = zero4;
  #pragma unroll
  for (int kk = 0; kk < 8; ++kk){
    bf16x8_t A[4];
    #pragma unroll
    for (int mt = 0; mt < 4; ++mt){
      int row = c + 16 * mt;
      A[mt] = *(const bf16x8_t*)&at[row * 256 + ((kk * 32 + 8 * h) ^ ((row & 7) << 3))];
    }
    #pragma unroll
    for (int nt = 0; nt < 4; ++nt){
      int d = 64 * w + 16 * nt + c;
      bf16x8_t Bv = *(const bf16x8_t*)(wkt + (size_t)d * 256 + kk * 32 + 8 * h);
      #pragma unroll
      for (int mt = 0; mt < 4; ++mt) acc[mt][nt] = MFMA16(A[mt], Bv, acc[mt][nt]);
    }
  }
  #pragma unroll
  for (int mt = 0; mt < 4; ++mt)
    #pragma unroll
    for (int nt = 0; nt < 4; ++nt)
      #pragma unroll
      for (int i = 0; i < 4; ++i){
        size_t row = r0 + 16 * mt + 4 * h + i;
        int d = 64 * w + 16 * nt + c;
        qkp[row * 256 + d] = f2b(acc[mt][nt][i]);
      }
}

// ---------------- fused attention: one block per batch ----------------
__global__ __launch_bounds__(256, 2) void attn_main(
    const float* __restrict__ keys, const int* __restrict__ mask,
    const unsigned short* __restrict__ qkp, const unsigned short* __restrict__ wvb,
    float* __restrict__ out){
  __shared__ unsigned short keysb[64 * 256];   // [t][d] bf16, swizzled  (32 KB)
  __shared__ unsigned short vT[256 * 64];      // [e][t] bf16, swizzled  (32 KB)
  __shared__ unsigned short Pl[32 * 64];       // [q][t] bf16, swizzled  (4 KB)
  __shared__ float denom[32];

  int b = blockIdx.x;
  int tid = threadIdx.x, w = tid >> 6, l = tid & 63, h = l >> 4, c = l & 15;

  // n_real = sum(mask row), every wave computes the full row (L2-hot)
  int s_ = 0;
  #pragma unroll
  for (int j = 0; j < 8; ++j) s_ += mask[(size_t)b * 512 + j * 64 + l];
  #pragma unroll
  for (int k = 1; k < 64; k <<= 1) s_ += __shfl_xor(s_, k);
  int n_real = s_ < 1 ? 1 : (s_ > 512 ? 512 : s_);

  if (tid < 32) denom[tid] = 0.f;

  // qkp fragments (B-operand of logits MFMA), resident in registers per wave
  bf16x8_t qf[2][8];
  #pragma unroll
  for (int nt = 0; nt < 2; ++nt)
    #pragma unroll
    for (int kk = 0; kk < 8; ++kk)
      qf[nt][kk] = *(const bf16x8_t*)(qkp + ((size_t)b * 32 + 16 * nt + c) * 256 + kk * 32 + 8 * h);

  float slope0 = exp2f(-2.0f * (float)((c & 3) + 1));   // head = q&3, same for q=c and q=c+16

  f32x4_t zero4 = {0.f, 0.f, 0.f, 0.f};
  f32x4_t ao[2][4];
  #pragma unroll
  for (int qt = 0; qt < 2; ++qt)
    #pragma unroll
    for (int nt = 0; nt < 4; ++nt) ao[qt][nt] = zero4;

  int ntiles = (n_real + 63) >> 6;
  for (int it = 0; it < ntiles; ++it){
    int s0 = it * 64;
    // ---- STAGE keys tile -> bf16 LDS (swizzled) ----
    #pragma unroll
    for (int j = 0; j < 16; ++j){
      int f = j * 256 + tid;
      int t = f >> 6, d4 = (f & 63) * 4;
      float4 kv = *(const float4*)(keys + ((size_t)b * 512 + s0 + t) * 256 + d4);
      uint2 p;
      p.x = (unsigned)f2b(kv.x) | ((unsigned)f2b(kv.y) << 16);
      p.y = (unsigned)f2b(kv.z) | ((unsigned)f2b(kv.w) << 16);
      *(uint2*)&keysb[t * 256 + (d4 ^ ((t & 7) << 3))] = p;
    }
    __syncthreads();

    // ---- V-projection + logits (share A-fragments) ----
    f32x4_t av[4][4];
    #pragma unroll
    for (int mt = 0; mt < 4; ++mt)
      #pragma unroll
      for (int nt = 0; nt < 4; ++nt) av[mt][nt] = zero4;
    f32x4_t as0 = zero4, as1 = zero4;

    #pragma unroll
    for (int kk = 0; kk < 8; ++kk){
      bf16x8_t A[4];
      #pragma unroll
      for (int mt = 0; mt < 4; ++mt){
        int row = c + 16 * mt;
        A[mt] = *(const bf16x8_t*)&keysb[row * 256 + ((kk * 32 + 8 * h) ^ ((row & 7) << 3))];
        if (mt == w){   // wave w owns logits t-range [16w,16w+16)
          as0 = MFMA16(A[mt], qf[0][kk], as0);
          as1 = MFMA16(A[mt], qf[1][kk], as1);
        }
      }
      #pragma unroll
      for (int nt = 0; nt < 4; ++nt){
        int e = 64 * w + 16 * nt + c;
        bf16x8_t Bv = *(const bf16x8_t*)(wvb + (size_t)e * 256 + kk * 32 + 8 * h);
        #pragma unroll
        for (int mt = 0; mt < 4; ++mt) av[mt][nt] = MFMA16(A[mt], Bv, av[mt][nt]);
      }
    }
    // write v transposed: vT[e][t], lane holds 4 consecutive t per (mt,nt)
    #pragma unroll
    for (int mt = 0; mt < 4; ++mt)
      #pragma unroll
      for (int nt = 0; nt < 4; ++nt){
        int e = 64 * w + 16 * nt + c;
        int t0 = 16 * mt + 4 * h;
        uint2 p;
        p.x = (unsigned)f2b(av[mt][nt][0]) | ((unsigned)f2b(av[mt][nt][1]) << 16);
        p.y = (unsigned)f2b(av[mt][nt][2]) | ((unsigned)f2b(av[mt][nt][3]) << 16);
        *(uint2*)&vT[e * 64 + (t0 ^ ((e & 7) << 3))] = p;
      }

    // ---- softmax (fixed-max): e = exp(logit - slope*games_ago), masked -> 0 ----
    {
      float e0[4], e1[4];
      float q0s = 0.f, q1s = 0.f;
      #pragma unroll
      for (int i = 0; i < 4; ++i){
        int s = s0 + 16 * w + 4 * h + i;
        float ga = (float)(n_real - 1 - s);
        bool valid = (s < n_real);
        float v0 = valid ? __expf(as0[i] - slope0 * ga) : 0.f;
        float v1 = valid ? __expf(as1[i] - slope0 * ga) : 0.f;
        e0[i] = v0; e1[i] = v1; q0s += v0; q1s += v1;
      }
      float r0 = q0s + __shfl_xor(q0s, 16); r0 += __shfl_xor(r0, 32);
      float r1 = q1s + __shfl_xor(q1s, 16); r1 += __shfl_xor(r1, 32);
      if (l < 16){ atomicAdd(&denom[c], r0); atomicAdd(&denom[c + 16], r1); }
      int t0 = 16 * w + 4 * h;
      uint2 p0, p1;
      p0.x = (unsigned)f2b(e0[0]) | ((unsigned)f2b(e0[1]) << 16);
      p0.y = (unsigned)f2b(e0[2]) | ((unsigned)f2b(e0[3]) << 16);
      p1.x = (unsigned)f2b(e1[0]) | ((unsigned)f2b(e1[1]) << 16);
      p1.y = (unsigned)f2b(e1[2]) | ((unsigned)f2b(e1[3]) << 16);
      *(uint2*)&Pl[c * 64 + (t0 ^ ((c & 7) << 3))] = p0;
      *(uint2*)&Pl[(c + 16) * 64 + (t0 ^ ((c & 7) << 3))] = p1;
    }
    __syncthreads();

    // ---- PV: ao[q][d] += P[q][t] * v[t][d] ----
    #pragma unroll
    for (int kk = 0; kk < 2; ++kk){
      int t0 = kk * 32 + 8 * h;
      bf16x8_t Ap0 = *(const bf16x8_t*)&Pl[c * 64 + (t0 ^ ((c & 7) << 3))];
      bf16x8_t Ap1 = *(const bf16x8_t*)&Pl[(c + 16) * 64 + (t0 ^ ((c & 7) << 3))];
      #pragma unroll
      for (int nt = 0; nt < 4; ++nt){
        int d = 64 * w + 16 * nt + c;
        bf16x8_t Bv = *(const bf16x8_t*)&vT[d * 64 + (t0 ^ ((d & 7) << 3))];
        ao[0][nt] = MFMA16(Ap0, Bv, ao[0][nt]);
        ao[1][nt] = MFMA16(Ap1, Bv, ao[1][nt]);
      }
    }
    __syncthreads();
  }

  // ---- normalize + store ----
  #pragma unroll
  for (int qt = 0; qt < 2; ++qt){
    float id[4];
    #pragma unroll
    for (int i = 0; i < 4; ++i) id[i] = 1.f / denom[16 * qt + 4 * h + i];
    #pragma unroll
    for (int nt = 0; nt < 4; ++nt){
      int d = 64 * w + 16 * nt + c;
      #pragma unroll
      for (int i = 0; i < 4; ++i){
        int q = 16 * qt + 4 * h + i;
        out[((size_t)b * 32 + q) * 256 + d] = ao[qt][nt][i] * id[i];
      }
    }
  }
}

extern "C" void kernel_launch(void* const* d_in, const int* in_sizes, int n_in,
                              void* d_out, int out_size, void* d_ws, size_t ws_size,
                              hipStream_t stream){
  const float* keys    = (const float*)d_in[0];
  const int*   mask    = (const int*)d_in[1];
  const float* context = (const float*)d_in[2];
  const float* queries = (const float*)d_in[3];
  const float* key_w   = (const float*)d_in[4];
  const float* value_w = (const float*)d_in[5];
  const float* logt    = (const float*)d_in[6];
  const float* cond_w  = (const float*)d_in[7];
  const float* cond_b  = (const float*)d_in[8];
  float* out = (float*)d_out;

  unsigned short* wvb = (unsigned short*)d_ws;           // 65536
  unsigned short* wkt = wvb + 65536;                     // 65536
  unsigned short* qs  = wkt + 65536;                     // 16384*256
  unsigned short* qkp = qs + (size_t)16384 * 256;        // 16384*256

  hipLaunchKernelGGL(prep_w,   dim3(256), dim3(256), 0, stream, key_w, value_w, wvb, wkt);
  hipLaunchKernelGGL(calc_qs,  dim3(256), dim3(256), 0, stream, context, queries, logt, cond_w, cond_b, qs);
  hipLaunchKernelGGL(calc_qkp, dim3(256), dim3(256), 0, stream, qs, wkt, qkp);
  hipLaunchKernelGGL(attn_main, dim3(512), dim3(256), 0, stream, keys, mask, qkp, wvb, out);
}

// Round 2
// 321.598 us; speedup vs baseline: 1.0135x; 1.0135x over previous
//
#include <hip/hip_runtime.h>

typedef short bf16x8_t __attribute__((ext_vector_type(8)));
typedef float f32x4_t  __attribute__((ext_vector_type(4)));

#define MFMA16(a,b,c) __builtin_amdgcn_mfma_f32_16x16x32_bf16(a,b,c,0,0,0)

__device__ __forceinline__ unsigned short f2b(float x){
  unsigned u = __float_as_uint(x);
  u += 0x7fffu + ((u >> 16) & 1u);
  return (unsigned short)(u >> 16);
}

// ---------------- prep: Wv -> bf16 rowmajor [e][d]; WkT[d][e] = bf16(key_w[e][d]) ----------------
__global__ void prep_w(const float* __restrict__ kw, const float* __restrict__ vw,
                       unsigned short* __restrict__ wvb, unsigned short* __restrict__ wktb){
  int i = blockIdx.x * 256 + threadIdx.x;          // 0..65535
  wvb[i] = f2b(vw[i]);
  int d = i >> 8, e = i & 255;
  wktb[i] = f2b(kw[e * 256 + d]);
}

// ---------------- n_real[b] = clamp(sum mask row) ----------------
__global__ void nreal_k(const int* __restrict__ mask, int* __restrict__ nreal){
  int b = blockIdx.x, l = threadIdx.x;
  int s_ = 0;
  #pragma unroll
  for (int j = 0; j < 8; ++j) s_ += mask[(size_t)b * 512 + j * 64 + l];
  #pragma unroll
  for (int k = 1; k < 64; k <<= 1) s_ += __shfl_xor(s_, k);
  if (l == 0) nreal[b] = s_ < 1 ? 1 : (s_ > 512 ? 512 : s_);
}

// ---------------- zero out + denom ----------------
__global__ void zero_k(float4* __restrict__ out4, float4* __restrict__ den4){
  int i = blockIdx.x * 256 + threadIdx.x;
  float4 z = {0.f, 0.f, 0.f, 0.f};
  out4[i] = z;                 // grid covers exactly 1048576 float4
  if (i < 4096) den4[i] = z;
}

// ---------------- qs[b*32+q][e] = (queries[q,e] + context[b]@cond_w[q*256+e] + cond_b)*scale*inv_t ----------------
__global__ __launch_bounds__(256) void calc_qs(
    const float* __restrict__ context, const float* __restrict__ queries,
    const float* __restrict__ logt, const float* __restrict__ condw,
    const float* __restrict__ condb, unsigned short* __restrict__ qs){
  __shared__ float ctx_l[64 * 64];
  int tid = threadIdx.x;
  int q   = blockIdx.x & 31;
  int b0  = (blockIdx.x >> 5) * 64;
  int qd  = q * 256 + tid;
  float4 cw[16];
  #pragma unroll
  for (int j = 0; j < 16; ++j) cw[j] = *(const float4*)(condw + (size_t)qd * 64 + 4 * j);
  float qbias = queries[qd] + condb[qd];
  float sc = 0.0625f * __expf(-logt[q >> 2]);      // scale * inv_temperature
  #pragma unroll
  for (int j = 0; j < 16; ++j){
    int f = j * 256 + tid;
    ctx_l[f] = context[(size_t)b0 * 64 + f];
  }
  __syncthreads();
  for (int b = 0; b < 64; ++b){
    const float4* cl = (const float4*)(ctx_l + b * 64);
    float acc = 0.f;
    #pragma unroll
    for (int j = 0; j < 16; ++j){
      float4 cv = cl[j]; float4 w4 = cw[j];
      acc += cv.x * w4.x + cv.y * w4.y + cv.z * w4.z + cv.w * w4.w;
    }
    qs[((size_t)(b0 + b) * 32 + q) * 256 + tid] = f2b((qbias + acc) * sc);
  }
}

// ---------------- qkp[row][d] = sum_e qs[row][e] * WkT[d][e]   (row = b*32+q) ----------------
__global__ __launch_bounds__(256) void calc_qkp(
    const unsigned short* __restrict__ qs, const unsigned short* __restrict__ wkt,
    unsigned short* __restrict__ qkp){
  __shared__ unsigned short at[64 * 256];
  int tid = threadIdx.x, w = tid >> 6, l = tid & 63, h = l >> 4, c = l & 15;
  size_t r0 = (size_t)blockIdx.x * 64;
  #pragma unroll
  for (int j = 0; j < 8; ++j){
    int f = j * 256 + tid;
    int row = f >> 5, col = (f & 31) * 8;
    bf16x8_t v = *(const bf16x8_t*)(qs + (r0 + row) * 256 + col);
    *(bf16x8_t*)&at[row * 256 + (col ^ ((row & 7) << 3))] = v;
  }
  __syncthreads();
  f32x4_t zero4 = {0.f, 0.f, 0.f, 0.f};
  f32x4_t acc[4][4];
  #pragma unroll
  for (int mt = 0; mt < 4; ++mt)
    #pragma unroll
    for (int nt = 0; nt < 4; ++nt) acc[mt][nt] = zero4;
  #pragma unroll
  for (int kk = 0; kk < 8; ++kk){
    bf16x8_t A[4];
    #pragma unroll
    for (int mt = 0; mt < 4; ++mt){
      int row = c + 16 * mt;
      A[mt] = *(const bf16x8_t*)&at[row * 256 + ((kk * 32 + 8 * h) ^ ((row & 7) << 3))];
    }
    #pragma unroll
    for (int nt = 0; nt < 4; ++nt){
      int d = 64 * w + 16 * nt + c;
      bf16x8_t Bv = *(const bf16x8_t*)(wkt + (size_t)d * 256 + kk * 32 + 8 * h);
      #pragma unroll
      for (int mt = 0; mt < 4; ++mt) acc[mt][nt] = MFMA16(A[mt], Bv, acc[mt][nt]);
    }
  }
  #pragma unroll
  for (int mt = 0; mt < 4; ++mt)
    #pragma unroll
    for (int nt = 0; nt < 4; ++nt)
      #pragma unroll
      for (int i = 0; i < 4; ++i){
        size_t row = r0 + 16 * mt + 4 * h + i;
        int d = 64 * w + 16 * nt + c;
        qkp[row * 256 + d] = f2b(acc[mt][nt][i]);
      }
}

// ---------------- partial attention: one block per (batch, 128-pos chunk) ----------------
// Fixed-max softmax => numerators and denominators are additive across chunks.
__global__ __launch_bounds__(256, 2) void attn_part(
    const float* __restrict__ keys, const int* __restrict__ nreal,
    const unsigned short* __restrict__ qkp, const unsigned short* __restrict__ wvb,
    float* __restrict__ out, float* __restrict__ deng){
  __shared__ unsigned short smem[64 * 256];    // keysb [t][d] / vT [e][t] union (32 KB)
  __shared__ unsigned short qkl[32 * 256];     // qkp rows for this b, swizzled (16 KB)
  __shared__ unsigned short Pl[32 * 64];       // [q][t] bf16, swizzled (4 KB)
  __shared__ float denl[32];

  int bid = blockIdx.x;
  int b = bid >> 2, ch = bid & 3;
  int n_real = nreal[b];
  int sbase = ch * 128;
  if (sbase >= n_real) return;                 // uniform early-exit, before any barrier

  int tid = threadIdx.x, w = tid >> 6, l = tid & 63, h = l >> 4, c = l & 15;
  if (tid < 32) denl[tid] = 0.f;

  // stage qkp[b] -> LDS (swizzled), replaces 64 resident VGPRs of the old design
  #pragma unroll
  for (int j = 0; j < 4; ++j){
    int f = j * 2048 + tid * 8;
    int row = f >> 8, col = f & 255;
    bf16x8_t v = *(const bf16x8_t*)(qkp + ((size_t)b * 32 + row) * 256 + col);
    *(bf16x8_t*)&qkl[row * 256 + (col ^ ((row & 7) << 3))] = v;
  }

  float slope0 = exp2f(-2.0f * (float)((c & 3) + 1));   // head = q&3 (same for q=c, c+16)

  f32x4_t zero4 = {0.f, 0.f, 0.f, 0.f};
  f32x4_t ao[2][4];
  #pragma unroll
  for (int qt = 0; qt < 2; ++qt)
    #pragma unroll
    for (int nt = 0; nt < 4; ++nt) ao[qt][nt] = zero4;

  int tend = (n_real - sbase + 63) >> 6; if (tend > 2) tend = 2;
  for (int it = 0; it < tend; ++it){
    int s0 = sbase + it * 64;
    // ---- STAGE keys tile -> bf16 LDS (swizzled) ----
    #pragma unroll
    for (int j = 0; j < 16; ++j){
      int f = j * 256 + tid;
      int t = f >> 6, d4 = (f & 63) * 4;
      float4 kv = *(const float4*)(keys + ((size_t)b * 512 + s0 + t) * 256 + d4);
      uint2 p;
      p.x = (unsigned)f2b(kv.x) | ((unsigned)f2b(kv.y) << 16);
      p.y = (unsigned)f2b(kv.z) | ((unsigned)f2b(kv.w) << 16);
      *(uint2*)&smem[t * 256 + (d4 ^ ((t & 7) << 3))] = p;
    }
    __syncthreads();

    // ---- V-projection + logits (share A-fragments) ----
    f32x4_t av[4][4];
    #pragma unroll
    for (int mt = 0; mt < 4; ++mt)
      #pragma unroll
      for (int nt = 0; nt < 4; ++nt) av[mt][nt] = zero4;
    f32x4_t as0 = zero4, as1 = zero4;

    #pragma unroll
    for (int kk = 0; kk < 8; ++kk){
      int colk = (kk * 32 + 8 * h);
      bf16x8_t q0 = *(const bf16x8_t*)&qkl[c * 256 + (colk ^ ((c & 7) << 3))];
      bf16x8_t q1 = *(const bf16x8_t*)&qkl[(c + 16) * 256 + (colk ^ ((c & 7) << 3))];
      bf16x8_t A[4];
      #pragma unroll
      for (int mt = 0; mt < 4; ++mt){
        int row = c + 16 * mt;
        A[mt] = *(const bf16x8_t*)&smem[row * 256 + (colk ^ ((row & 7) << 3))];
        if (mt == w){   // wave w owns logits t-range [16w,16w+16)
          as0 = MFMA16(A[mt], q0, as0);
          as1 = MFMA16(A[mt], q1, as1);
        }
      }
      #pragma unroll
      for (int nt = 0; nt < 4; ++nt){
        int e = 64 * w + 16 * nt + c;
        bf16x8_t Bv = *(const bf16x8_t*)(wvb + (size_t)e * 256 + colk);
        #pragma unroll
        for (int mt = 0; mt < 4; ++mt) av[mt][nt] = MFMA16(A[mt], Bv, av[mt][nt]);
      }
    }
    __syncthreads();   // all keysb reads done before vT overwrites (union)

    // ---- vT[e][t] <- av (aliased over keysb) ----
    #pragma unroll
    for (int mt = 0; mt < 4; ++mt)
      #pragma unroll
      for (int nt = 0; nt < 4; ++nt){
        int e = 64 * w + 16 * nt + c;
        int t0 = 16 * mt + 4 * h;
        uint2 p;
        p.x = (unsigned)f2b(av[mt][nt][0]) | ((unsigned)f2b(av[mt][nt][1]) << 16);
        p.y = (unsigned)f2b(av[mt][nt][2]) | ((unsigned)f2b(av[mt][nt][3]) << 16);
        *(uint2*)&smem[e * 64 + (t0 ^ ((e & 7) << 3))] = p;
      }

    // ---- softmax (fixed-max): P = exp(logit - slope*games_ago), masked -> 0 ----
    {
      float e0[4], e1[4];
      float q0s = 0.f, q1s = 0.f;
      #pragma unroll
      for (int i = 0; i < 4; ++i){
        int s = s0 + 16 * w + 4 * h + i;
        float ga = (float)(n_real - 1 - s);
        bool valid = (s < n_real);
        float v0 = valid ? __expf(as0[i] - slope0 * ga) : 0.f;
        float v1 = valid ? __expf(as1[i] - slope0 * ga) : 0.f;
        e0[i] = v0; e1[i] = v1; q0s += v0; q1s += v1;
      }
      float r0 = q0s + __shfl_xor(q0s, 16); r0 += __shfl_xor(r0, 32);
      float r1 = q1s + __shfl_xor(q1s, 16); r1 += __shfl_xor(r1, 32);
      if (l < 16){ atomicAdd(&denl[c], r0); atomicAdd(&denl[c + 16], r1); }
      int t0 = 16 * w + 4 * h;
      uint2 p0, p1;
      p0.x = (unsigned)f2b(e0[0]) | ((unsigned)f2b(e0[1]) << 16);
      p0.y = (unsigned)f2b(e0[2]) | ((unsigned)f2b(e0[3]) << 16);
      p1.x = (unsigned)f2b(e1[0]) | ((unsigned)f2b(e1[1]) << 16);
      p1.y = (unsigned)f2b(e1[2]) | ((unsigned)f2b(e1[3]) << 16);
      *(uint2*)&Pl[c * 64 + (t0 ^ ((c & 7) << 3))] = p0;
      *(uint2*)&Pl[(c + 16) * 64 + (t0 ^ ((c & 7) << 3))] = p1;
    }
    __syncthreads();

    // ---- PV: ao[q][d] += P[q][t] * v[t][d] ----
    #pragma unroll
    for (int kk = 0; kk < 2; ++kk){
      int t0 = kk * 32 + 8 * h;
      bf16x8_t Ap0 = *(const bf16x8_t*)&Pl[c * 64 + (t0 ^ ((c & 7) << 3))];
      bf16x8_t Ap1 = *(const bf16x8_t*)&Pl[(c + 16) * 64 + (t0 ^ ((c & 7) << 3))];
      #pragma unroll
      for (int nt = 0; nt < 4; ++nt){
        int d = 64 * w + 16 * nt + c;
        bf16x8_t Bv = *(const bf16x8_t*)&smem[d * 64 + (t0 ^ ((d & 7) << 3))];
        ao[0][nt] = MFMA16(Ap0, Bv, ao[0][nt]);
        ao[1][nt] = MFMA16(Ap1, Bv, ao[1][nt]);
      }
    }
    __syncthreads();   // vT fully consumed before next restage
  }

  // ---- accumulate partial numerators / denominators ----
  #pragma unroll
  for (int qt = 0; qt < 2; ++qt)
    #pragma unroll
    for (int nt = 0; nt < 4; ++nt){
      int d = 64 * w + 16 * nt + c;
      #pragma unroll
      for (int i = 0; i < 4; ++i){
        int q = 16 * qt + 4 * h + i;
        atomicAdd(&out[((size_t)b * 32 + q) * 256 + d], ao[qt][nt][i]);
      }
    }
  if (tid < 32) atomicAdd(&deng[b * 32 + tid], denl[tid]);
}

// ---------------- normalize: out /= denom ----------------
__global__ void norm_k(float4* __restrict__ out4, const float* __restrict__ deng){
  int i = blockIdx.x * 256 + threadIdx.x;      // 0..1048575 float4s
  float inv = 1.f / deng[i >> 6];              // i4>>6 == (b*32+q)
  float4 v = out4[i];
  v.x *= inv; v.y *= inv; v.z *= inv; v.w *= inv;
  out4[i] = v;
}

extern "C" void kernel_launch(void* const* d_in, const int* in_sizes, int n_in,
                              void* d_out, int out_size, void* d_ws, size_t ws_size,
                              hipStream_t stream){
  const float* keys    = (const float*)d_in[0];
  const int*   mask    = (const int*)d_in[1];
  const float* context = (const float*)d_in[2];
  const float* queries = (const float*)d_in[3];
  const float* key_w   = (const float*)d_in[4];
  const float* value_w = (const float*)d_in[5];
  const float* logt    = (const float*)d_in[6];
  const float* cond_w  = (const float*)d_in[7];
  const float* cond_b  = (const float*)d_in[8];
  float* out = (float*)d_out;

  unsigned short* wvb = (unsigned short*)d_ws;           // 65536
  unsigned short* wkt = wvb + 65536;                     // 65536
  unsigned short* qs  = wkt + 65536;                     // 16384*256
  unsigned short* qkp = qs + (size_t)16384 * 256;        // 16384*256
  float* deng = (float*)(qkp + (size_t)16384 * 256);     // 16384 f32
  int*   nreal = (int*)(deng + 16384);                   // 512 int

  hipLaunchKernelGGL(prep_w,   dim3(256), dim3(256), 0, stream, key_w, value_w, wvb, wkt);
  hipLaunchKernelGGL(nreal_k,  dim3(512), dim3(64),  0, stream, mask, nreal);
  hipLaunchKernelGGL(zero_k,   dim3(4096), dim3(256), 0, stream, (float4*)out, (float4*)deng);
  hipLaunchKernelGGL(calc_qs,  dim3(256), dim3(256), 0, stream, context, queries, logt, cond_w, cond_b, qs);
  hipLaunchKernelGGL(calc_qkp, dim3(256), dim3(256), 0, stream, qs, wkt, qkp);
  hipLaunchKernelGGL(attn_part, dim3(2048), dim3(256), 0, stream, keys, nreal, qkp, wvb, out, deng);
  hipLaunchKernelGGL(norm_k,   dim3(4096), dim3(256), 0, stream, (float4*)out, deng);
}

// Round 3
// 187.362 us; speedup vs baseline: 1.7397x; 1.7165x over previous
//
#include <hip/hip_runtime.h>

typedef short bf16x8_t __attribute__((ext_vector_type(8)));
typedef float f32x4_t  __attribute__((ext_vector_type(4)));

#define MFMA16(a,b,c) __builtin_amdgcn_mfma_f32_16x16x32_bf16(a,b,c,0,0,0)

__device__ __forceinline__ unsigned short f2b(float x){
  unsigned u = __float_as_uint(x);
  u += 0x7fffu + ((u >> 16) & 1u);
  return (unsigned short)(u >> 16);
}

__device__ __forceinline__ void gload16(const float* g, void* l){
  __builtin_amdgcn_global_load_lds(
      (const __attribute__((address_space(1))) void*)g,
      (__attribute__((address_space(3))) void*)l, 16, 0, 0);
}

// ---------------- prep: Wv -> bf16 rowmajor [e][d]; WkT[d][e] = bf16(key_w[e][d]) ----------------
__global__ void prep_w(const float* __restrict__ kw, const float* __restrict__ vw,
                       unsigned short* __restrict__ wvb, unsigned short* __restrict__ wktb){
  int i = blockIdx.x * 256 + threadIdx.x;          // 0..65535
  wvb[i] = f2b(vw[i]);
  int d = i >> 8, e = i & 255;
  wktb[i] = f2b(kw[e * 256 + d]);
}

// ---------------- n_real[b] = clamp(sum mask row) ----------------
__global__ void nreal_k(const int* __restrict__ mask, int* __restrict__ nreal){
  int b = blockIdx.x, l = threadIdx.x;
  int s_ = 0;
  #pragma unroll
  for (int j = 0; j < 8; ++j) s_ += mask[(size_t)b * 512 + j * 64 + l];
  #pragma unroll
  for (int k = 1; k < 64; k <<= 1) s_ += __shfl_xor(s_, k);
  if (l == 0) nreal[b] = s_ < 1 ? 1 : (s_ > 512 ? 512 : s_);
}

// ---------------- zero out + denom ----------------
__global__ void zero_k(float4* __restrict__ out4, float4* __restrict__ den4){
  int i = blockIdx.x * 256 + threadIdx.x;
  float4 z = {0.f, 0.f, 0.f, 0.f};
  out4[i] = z;                 // grid covers exactly 1048576 float4
  if (i < 4096) den4[i] = z;
}

// ---------------- qs[b*32+q][e] = (queries[q,e] + context[b]@cond_w[q*256+e] + cond_b)*scale*inv_t ----------------
__global__ __launch_bounds__(256) void calc_qs(
    const float* __restrict__ context, const float* __restrict__ queries,
    const float* __restrict__ logt, const float* __restrict__ condw,
    const float* __restrict__ condb, unsigned short* __restrict__ qs){
  __shared__ float ctx_l[64 * 64];
  int tid = threadIdx.x;
  int q   = blockIdx.x & 31;
  int b0  = (blockIdx.x >> 5) * 64;
  int qd  = q * 256 + tid;
  float4 cw[16];
  #pragma unroll
  for (int j = 0; j < 16; ++j) cw[j] = *(const float4*)(condw + (size_t)qd * 64 + 4 * j);
  float qbias = queries[qd] + condb[qd];
  float sc = 0.0625f * __expf(-logt[q >> 2]);      // scale * inv_temperature
  #pragma unroll
  for (int j = 0; j < 16; ++j){
    int f = j * 256 + tid;
    ctx_l[f] = context[(size_t)b0 * 64 + f];
  }
  __syncthreads();
  for (int b = 0; b < 64; ++b){
    const float4* cl = (const float4*)(ctx_l + b * 64);
    float acc = 0.f;
    #pragma unroll
    for (int j = 0; j < 16; ++j){
      float4 cv = cl[j]; float4 w4 = cw[j];
      acc += cv.x * w4.x + cv.y * w4.y + cv.z * w4.z + cv.w * w4.w;
    }
    qs[((size_t)(b0 + b) * 32 + q) * 256 + tid] = f2b((qbias + acc) * sc);
  }
}

// ---------------- qkp[row][d] = sum_e qs[row][e] * WkT[d][e]   (row = b*32+q) ----------------
__global__ __launch_bounds__(256) void calc_qkp(
    const unsigned short* __restrict__ qs, const unsigned short* __restrict__ wkt,
    unsigned short* __restrict__ qkp){
  __shared__ unsigned short at[64 * 256];
  int tid = threadIdx.x, w = tid >> 6, l = tid & 63, h = l >> 4, c = l & 15;
  size_t r0 = (size_t)blockIdx.x * 64;
  #pragma unroll
  for (int j = 0; j < 8; ++j){
    int f = j * 256 + tid;
    int row = f >> 5, col = (f & 31) * 8;
    bf16x8_t v = *(const bf16x8_t*)(qs + (r0 + row) * 256 + col);
    *(bf16x8_t*)&at[row * 256 + (col ^ ((row & 7) << 3))] = v;
  }
  __syncthreads();
  f32x4_t zero4 = {0.f, 0.f, 0.f, 0.f};
  f32x4_t acc[4][4];
  #pragma unroll
  for (int mt = 0; mt < 4; ++mt)
    #pragma unroll
    for (int nt = 0; nt < 4; ++nt) acc[mt][nt] = zero4;
  #pragma unroll
  for (int kk = 0; kk < 8; ++kk){
    bf16x8_t A[4];
    #pragma unroll
    for (int mt = 0; mt < 4; ++mt){
      int row = c + 16 * mt;
      A[mt] = *(const bf16x8_t*)&at[row * 256 + ((kk * 32 + 8 * h) ^ ((row & 7) << 3))];
    }
    #pragma unroll
    for (int nt = 0; nt < 4; ++nt){
      int d = 64 * w + 16 * nt + c;
      bf16x8_t Bv = *(const bf16x8_t*)(wkt + (size_t)d * 256 + kk * 32 + 8 * h);
      #pragma unroll
      for (int mt = 0; mt < 4; ++mt) acc[mt][nt] = MFMA16(A[mt], Bv, acc[mt][nt]);
    }
  }
  #pragma unroll
  for (int mt = 0; mt < 4; ++mt)
    #pragma unroll
    for (int nt = 0; nt < 4; ++nt)
      #pragma unroll
      for (int i = 0; i < 4; ++i){
        size_t row = r0 + 16 * mt + 4 * h + i;
        int d = 64 * w + 16 * nt + c;
        qkp[row * 256 + d] = f2b(acc[mt][nt][i]);
      }
}

// ---------------- partial attention: one block per (batch, 128-pos chunk) ----------------
// TILE=32 rows. Async f32 staging via global_load_lds into F, convert F->K (bf16 swizzled).
__global__ __launch_bounds__(256) void attn_part(
    const float* __restrict__ keys, const int* __restrict__ nreal,
    const unsigned short* __restrict__ qkp, const unsigned short* __restrict__ wvb,
    float* __restrict__ out, float* __restrict__ deng){
  __shared__ float          F[32 * 256];   // raw f32 staging, 32 KB
  __shared__ unsigned short K[32 * 256];   // bf16 keys, swizzled, 16 KB
  __shared__ unsigned short vT[256 * 32];  // v transposed [e][t], 16 KB
  __shared__ unsigned short Pl[32 * 32];   // P [q][t] bf16, 2 KB
  __shared__ float denl[32];

  int bid = blockIdx.x;
  int b = bid >> 2, ch = bid & 3;
  int n_real = nreal[b];
  int sbase = ch * 128;
  if (sbase >= n_real) return;                 // uniform early-exit, before any barrier

  int tid = threadIdx.x, w = tid >> 6, l = tid & 63, h = l >> 4, c = l & 15;
  int mt = w & 1, qt = w >> 1;
  if (tid < 32) denl[tid] = 0.f;

  // this wave's qkp fragments (B-operand of logits MFMA) in registers
  bf16x8_t qf[8];
  #pragma unroll
  for (int kk = 0; kk < 8; ++kk)
    qf[kk] = *(const bf16x8_t*)(qkp + ((size_t)b * 32 + 16 * qt + c) * 256 + kk * 32 + 8 * h);

  float slope0 = exp2f(-2.0f * (float)((c & 3) + 1));   // head = q&3

  f32x4_t zero4 = {0.f, 0.f, 0.f, 0.f};
  f32x4_t ao[2][4];
  #pragma unroll
  for (int q2 = 0; q2 < 2; ++q2)
    #pragma unroll
    for (int nt = 0; nt < 4; ++nt) ao[q2][nt] = zero4;

  int tend = (n_real - sbase + 31) >> 5; if (tend > 4) tend = 4;

  // prologue: issue DMA for tile 0 (rows t = 4j + w, one 1KB row per instr)
  #pragma unroll
  for (int j = 0; j < 8; ++j){
    int t = 4 * j + w;
    gload16(keys + ((size_t)b * 512 + sbase + t) * 256 + l * 4, &F[t * 256 + l * 4]);
  }

  for (int it = 0; it < tend; ++it){
    int s0 = sbase + it * 32;
    __syncthreads();                    // B1: drains DMA -> F complete; K free

    // ---- convert F -> K (bf16, swizzled) ----
    #pragma unroll
    for (int j = 0; j < 8; ++j){
      int row = 4 * j + w;
      int d4 = l * 4;
      f32x4_t kv = *(const f32x4_t*)&F[row * 256 + d4];
      uint2 p;
      p.x = (unsigned)f2b(kv[0]) | ((unsigned)f2b(kv[1]) << 16);
      p.y = (unsigned)f2b(kv[2]) | ((unsigned)f2b(kv[3]) << 16);
      *(uint2*)&K[row * 256 + (d4 ^ ((row & 7) << 3))] = p;
    }
    __syncthreads();                    // B2: K ready; F free

    // ---- issue DMA for tile it+1 (overlaps with compute below) ----
    if (it + 1 < tend){
      int s1 = sbase + (it + 1) * 32;
      #pragma unroll
      for (int j = 0; j < 8; ++j){
        int t = 4 * j + w;
        gload16(keys + ((size_t)b * 512 + s1 + t) * 256 + l * 4, &F[t * 256 + l * 4]);
      }
    }

    // ---- V-projection + logits ----
    f32x4_t av[2][4];
    #pragma unroll
    for (int m = 0; m < 2; ++m)
      #pragma unroll
      for (int nt = 0; nt < 4; ++nt) av[m][nt] = zero4;
    f32x4_t as_ = zero4;

    #pragma unroll
    for (int kk = 0; kk < 8; ++kk){
      int colk = kk * 32 + 8 * h;
      bf16x8_t A0 = *(const bf16x8_t*)&K[c * 256 + (colk ^ ((c & 7) << 3))];
      bf16x8_t A1 = *(const bf16x8_t*)&K[(c + 16) * 256 + (colk ^ ((c & 7) << 3))];
      as_ = MFMA16(mt ? A1 : A0, qf[kk], as_);
      #pragma unroll
      for (int nt = 0; nt < 4; ++nt){
        int e = 64 * w + 16 * nt + c;
        bf16x8_t Bv = *(const bf16x8_t*)(wvb + (size_t)e * 256 + colk);
        av[0][nt] = MFMA16(A0, Bv, av[0][nt]);
        av[1][nt] = MFMA16(A1, Bv, av[1][nt]);
      }
    }

    // ---- vT[e][t] <- av (each wave writes its own e-range) ----
    #pragma unroll
    for (int m = 0; m < 2; ++m)
      #pragma unroll
      for (int nt = 0; nt < 4; ++nt){
        int e = 64 * w + 16 * nt + c;
        int t0 = 16 * m + 4 * h;
        uint2 p;
        p.x = (unsigned)f2b(av[m][nt][0]) | ((unsigned)f2b(av[m][nt][1]) << 16);
        p.y = (unsigned)f2b(av[m][nt][2]) | ((unsigned)f2b(av[m][nt][3]) << 16);
        *(uint2*)&vT[e * 32 + (t0 ^ ((e & 1) << 3))] = p;
      }

    // ---- softmax (fixed-max): P = exp(logit - slope*games_ago), masked -> 0 ----
    {
      float e_[4]; float qs_ = 0.f;
      #pragma unroll
      for (int i = 0; i < 4; ++i){
        int s = s0 + 16 * mt + 4 * h + i;
        float ga = (float)(n_real - 1 - s);
        bool valid = (s < n_real);
        float v = valid ? __expf(as_[i] - slope0 * ga) : 0.f;
        e_[i] = v; qs_ += v;
      }
      float r = qs_ + __shfl_xor(qs_, 16); r += __shfl_xor(r, 32);
      if (l < 16) atomicAdd(&denl[16 * qt + c], r);
      int q = 16 * qt + c;
      int t0 = 16 * mt + 4 * h;
      uint2 p;
      p.x = (unsigned)f2b(e_[0]) | ((unsigned)f2b(e_[1]) << 16);
      p.y = (unsigned)f2b(e_[2]) | ((unsigned)f2b(e_[3]) << 16);
      *(uint2*)&Pl[q * 32 + (t0 ^ ((q & 1) << 3))] = p;
    }
    __syncthreads();                    // B3: Pl/vT visible (also drains next-tile DMA)

    // ---- PV: ao[q][d] += P[q][t] * v[t][d]  (K-dim = 32 = one MFMA step) ----
    {
      bf16x8_t Ap0 = *(const bf16x8_t*)&Pl[c * 32 + ((8 * h) ^ ((c & 1) << 3))];
      bf16x8_t Ap1 = *(const bf16x8_t*)&Pl[(16 + c) * 32 + ((8 * h) ^ ((c & 1) << 3))];
      #pragma unroll
      for (int nt = 0; nt < 4; ++nt){
        int d = 64 * w + 16 * nt + c;
        bf16x8_t Bv = *(const bf16x8_t*)&vT[d * 32 + ((8 * h) ^ ((d & 1) << 3))];
        ao[0][nt] = MFMA16(Ap0, Bv, ao[0][nt]);
        ao[1][nt] = MFMA16(Ap1, Bv, ao[1][nt]);
      }
    }
  }

  // ---- accumulate partial numerators / denominators ----
  #pragma unroll
  for (int q2 = 0; q2 < 2; ++q2)
    #pragma unroll
    for (int nt = 0; nt < 4; ++nt){
      int d = 64 * w + 16 * nt + c;
      #pragma unroll
      for (int i = 0; i < 4; ++i){
        int q = 16 * q2 + 4 * h + i;
        atomicAdd(&out[((size_t)b * 32 + q) * 256 + d], ao[q2][nt][i]);
      }
    }
  __syncthreads();
  if (tid < 32) atomicAdd(&deng[b * 32 + tid], denl[tid]);
}

// ---------------- normalize: out /= denom ----------------
__global__ void norm_k(float4* __restrict__ out4, const float* __restrict__ deng){
  int i = blockIdx.x * 256 + threadIdx.x;      // 0..1048575 float4s
  float inv = 1.f / deng[i >> 6];              // i4>>6 == (b*32+q)
  float4 v = out4[i];
  v.x *= inv; v.y *= inv; v.z *= inv; v.w *= inv;
  out4[i] = v;
}

extern "C" void kernel_launch(void* const* d_in, const int* in_sizes, int n_in,
                              void* d_out, int out_size, void* d_ws, size_t ws_size,
                              hipStream_t stream){
  const float* keys    = (const float*)d_in[0];
  const int*   mask    = (const int*)d_in[1];
  const float* context = (const float*)d_in[2];
  const float* queries = (const float*)d_in[3];
  const float* key_w   = (const float*)d_in[4];
  const float* value_w = (const float*)d_in[5];
  const float* logt    = (const float*)d_in[6];
  const float* cond_w  = (const float*)d_in[7];
  const float* cond_b  = (const float*)d_in[8];
  float* out = (float*)d_out;

  unsigned short* wvb = (unsigned short*)d_ws;           // 65536
  unsigned short* wkt = wvb + 65536;                     // 65536
  unsigned short* qs  = wkt + 65536;                     // 16384*256
  unsigned short* qkp = qs + (size_t)16384 * 256;        // 16384*256
  float* deng = (float*)(qkp + (size_t)16384 * 256);     // 16384 f32
  int*   nreal = (int*)(deng + 16384);                   // 512 int

  hipLaunchKernelGGL(prep_w,   dim3(256), dim3(256), 0, stream, key_w, value_w, wvb, wkt);
  hipLaunchKernelGGL(nreal_k,  dim3(512), dim3(64),  0, stream, mask, nreal);
  hipLaunchKernelGGL(zero_k,   dim3(4096), dim3(256), 0, stream, (float4*)out, (float4*)deng);
  hipLaunchKernelGGL(calc_qs,  dim3(256), dim3(256), 0, stream, context, queries, logt, cond_w, cond_b, qs);
  hipLaunchKernelGGL(calc_qkp, dim3(256), dim3(256), 0, stream, qs, wkt, qkp);
  hipLaunchKernelGGL(attn_part, dim3(2048), dim3(256), 0, stream, keys, nreal, qkp, wvb, out, deng);
  hipLaunchKernelGGL(norm_k,   dim3(4096), dim3(256), 0, stream, (float4*)out, deng);
}

// Round 6
// 138.507 us; speedup vs baseline: 2.3533x; 1.3527x over previous
//
#include <hip/hip_runtime.h>

typedef short bf16x8_t __attribute__((ext_vector_type(8)));
typedef float f32x4_t  __attribute__((ext_vector_type(4)));

#define MFMA16(a,b,c) __builtin_amdgcn_mfma_f32_16x16x32_bf16(a,b,c,0,0,0)

__device__ __forceinline__ unsigned short f2b(float x){
  unsigned u = __float_as_uint(x);
  u += 0x7fffu + ((u >> 16) & 1u);
  return (unsigned short)(u >> 16);
}

__device__ __forceinline__ void bar_lgkm(){
  asm volatile("s_waitcnt lgkmcnt(0)" ::: "memory");
  __builtin_amdgcn_s_barrier();
  __builtin_amdgcn_sched_barrier(0);
}

// ---------------- prep: WkT[d][e] = bf16(key_w[e][d]) (transposed);  Wvb = bf16(value_w) as-is ----------------
// calc_qkp reduces over e with output d -> needs the transpose. vproj_norm reduces over d with
// output e' and B[k][n]=W[n*256+k] -> needs value_w UNtransposed (this was the R5 bug).
__global__ void prep_w(const float* __restrict__ kw, const float* __restrict__ vw,
                       unsigned short* __restrict__ wktb, unsigned short* __restrict__ wvb){
  int i = blockIdx.x * 256 + threadIdx.x;          // 0..65535
  int d = i >> 8, e = i & 255;
  wktb[i] = f2b(kw[e * 256 + d]);
  wvb[i]  = f2b(vw[i]);
}

// ---------------- n_real[b] = clamp(sum mask row) ----------------
__global__ void nreal_k(const int* __restrict__ mask, int* __restrict__ nreal){
  int b = blockIdx.x, l = threadIdx.x;
  int s_ = 0;
  #pragma unroll
  for (int j = 0; j < 8; ++j) s_ += mask[(size_t)b * 512 + j * 64 + l];
  #pragma unroll
  for (int k = 1; k < 64; k <<= 1) s_ += __shfl_xor(s_, k);
  if (l == 0) nreal[b] = s_ < 1 ? 1 : (s_ > 512 ? 512 : s_);
}

// ---------------- zero out(acc) + denom ----------------
__global__ void zero_k(float4* __restrict__ acc4, float4* __restrict__ den4){
  int i = blockIdx.x * 256 + threadIdx.x;
  float4 z = {0.f, 0.f, 0.f, 0.f};
  acc4[i] = z;                 // grid covers exactly 1048576 float4 (= d_out)
  if (i < 4096) den4[i] = z;
}

// ---------------- qs[b*32+q][e] = (queries[q,e] + context[b]@cond_w[q*256+e] + cond_b)*scale*inv_t ----------------
__global__ __launch_bounds__(256) void calc_qs(
    const float* __restrict__ context, const float* __restrict__ queries,
    const float* __restrict__ logt, const float* __restrict__ condw,
    const float* __restrict__ condb, unsigned short* __restrict__ qs){
  __shared__ float ctx_l[64 * 64];
  int tid = threadIdx.x;
  int q   = blockIdx.x & 31;
  int b0  = (blockIdx.x >> 5) * 64;
  int qd  = q * 256 + tid;
  float4 cw[16];
  #pragma unroll
  for (int j = 0; j < 16; ++j) cw[j] = *(const float4*)(condw + (size_t)qd * 64 + 4 * j);
  float qbias = queries[qd] + condb[qd];
  float sc = 0.0625f * __expf(-logt[q >> 2]);      // scale * inv_temperature
  #pragma unroll
  for (int j = 0; j < 16; ++j){
    int f = j * 256 + tid;
    ctx_l[f] = context[(size_t)b0 * 64 + f];
  }
  __syncthreads();
  for (int b = 0; b < 64; ++b){
    const float4* cl = (const float4*)(ctx_l + b * 64);
    float acc = 0.f;
    #pragma unroll
    for (int j = 0; j < 16; ++j){
      float4 cv = cl[j]; float4 w4 = cw[j];
      acc += cv.x * w4.x + cv.y * w4.y + cv.z * w4.z + cv.w * w4.w;
    }
    qs[((size_t)(b0 + b) * 32 + q) * 256 + tid] = f2b((qbias + acc) * sc);
  }
}

// ---------------- qkp[row][d] = sum_e qs[row][e] * key_w[e][d]   (row = b*32+q) ----------------
__global__ __launch_bounds__(256) void calc_qkp(
    const unsigned short* __restrict__ qs, const unsigned short* __restrict__ wkt,
    unsigned short* __restrict__ qkp){
  __shared__ unsigned short at[64 * 256];
  int tid = threadIdx.x, w = tid >> 6, l = tid & 63, h = l >> 4, c = l & 15;
  size_t r0 = (size_t)blockIdx.x * 64;
  #pragma unroll
  for (int j = 0; j < 8; ++j){
    int f = j * 256 + tid;
    int row = f >> 5, col = (f & 31) * 8;
    bf16x8_t v = *(const bf16x8_t*)(qs + (r0 + row) * 256 + col);
    *(bf16x8_t*)&at[row * 256 + (col ^ ((row & 7) << 3))] = v;
  }
  __syncthreads();
  f32x4_t zero4 = {0.f, 0.f, 0.f, 0.f};
  f32x4_t acc[4][4];
  #pragma unroll
  for (int mt = 0; mt < 4; ++mt)
    #pragma unroll
    for (int nt = 0; nt < 4; ++nt) acc[mt][nt] = zero4;
  #pragma unroll
  for (int kk = 0; kk < 8; ++kk){
    bf16x8_t A[4];
    #pragma unroll
    for (int mt = 0; mt < 4; ++mt){
      int row = c + 16 * mt;
      A[mt] = *(const bf16x8_t*)&at[row * 256 + ((kk * 32 + 8 * h) ^ ((row & 7) << 3))];
    }
    #pragma unroll
    for (int nt = 0; nt < 4; ++nt){
      int d = 64 * w + 16 * nt + c;
      bf16x8_t Bv = *(const bf16x8_t*)(wkt + (size_t)d * 256 + kk * 32 + 8 * h);
      #pragma unroll
      for (int mt = 0; mt < 4; ++mt) acc[mt][nt] = MFMA16(A[mt], Bv, acc[mt][nt]);
    }
  }
  #pragma unroll
  for (int mt = 0; mt < 4; ++mt)
    #pragma unroll
    for (int nt = 0; nt < 4; ++nt)
      #pragma unroll
      for (int i = 0; i < 4; ++i){
        size_t row = r0 + 16 * mt + 4 * h + i;
        int d = 64 * w + 16 * nt + c;
        qkp[row * 256 + d] = f2b(acc[mt][nt][i]);
      }
}

// ---------------- partial attention over RAW keys: one block per (batch, 256-pos chunk) ----------------
// acc[q,e] += sum_s P[q,s] * keys[s,e]  (accumulated into d_out); Wv applied in epilogue GEMM.
// Raw barriers (lgkmcnt only, NO vmcnt drain) keep next-tile staging loads in flight.
__global__ __launch_bounds__(256, 3) void attn_part(
    const float* __restrict__ keys, const int* __restrict__ nreal,
    const unsigned short* __restrict__ qkp,
    float* __restrict__ acc, float* __restrict__ deng){
  __shared__ unsigned short K[32 * 256];   // bf16 keys, swizzled, 16 KB
  __shared__ unsigned short vT[256 * 32];  // K^T [e][t], swizzled, 16 KB
  __shared__ unsigned short Pl[32 * 32];   // P [q][t] bf16, 2 KB
  __shared__ float denl[32];

  int bid = blockIdx.x;
  int b = bid >> 1, ch = bid & 1;
  int n_real = nreal[b];
  int sbase = ch * 256;
  if (sbase >= n_real) return;                 // uniform early-exit, before any barrier

  int tid = threadIdx.x, w = tid >> 6, l = tid & 63, h = l >> 4, c = l & 15;
  int mt = w & 1, qt = w >> 1;
  if (tid < 32) denl[tid] = 0.f;

  // identity B-fragments for MFMA-transpose (exact for bf16 inputs)
  bf16x8_t bIe, bIo;
  #pragma unroll
  for (int j = 0; j < 8; ++j){
    bIe[j] = (h == (c >> 3)     && j == (c & 7)) ? (short)0x3F80 : (short)0;
    bIo[j] = (h == 2 + (c >> 3) && j == (c & 7)) ? (short)0x3F80 : (short)0;
  }

  // stage tile 0 into registers (8 x dwordx4 per lane; rows t = 4j + w, cols 4l..4l+3)
  const float* kptr = keys + ((size_t)b * 512 + sbase + w) * 256 + 4 * l;
  float4 R[8];
  #pragma unroll
  for (int j = 0; j < 8; ++j) R[j] = *(const float4*)(kptr + j * 1024);

  // this wave's qkp fragments (B-operand of logits MFMA)
  bf16x8_t qf[8];
  #pragma unroll
  for (int kk = 0; kk < 8; ++kk)
    qf[kk] = *(const bf16x8_t*)(qkp + ((size_t)b * 32 + 16 * qt + c) * 256 + kk * 32 + 8 * h);

  float slope0 = exp2f(-2.0f * (float)((c & 3) + 1));   // head = q&3

  f32x4_t zero4 = {0.f, 0.f, 0.f, 0.f};
  f32x4_t ao[2][4];
  #pragma unroll
  for (int q2 = 0; q2 < 2; ++q2)
    #pragma unroll
    for (int nt = 0; nt < 4; ++nt) ao[q2][nt] = zero4;

  int tend = (n_real - sbase + 31) >> 5; if (tend > 8) tend = 8;

  for (int it = 0; it < tend; ++it){
    int s0 = sbase + it * 32;
    // ---- convert R -> K (bf16, swizzled); interleave issue of next tile's loads ----
    const float* knext = kptr + (size_t)(it + 1) * (32 * 256);
    #pragma unroll
    for (int j = 0; j < 8; ++j){
      int row = 4 * j + w;
      int d4 = 4 * l;
      float4 kv = R[j];
      if (it + 1 < tend) R[j] = *(const float4*)(knext + j * 1024);
      uint2 p;
      p.x = (unsigned)f2b(kv.x) | ((unsigned)f2b(kv.y) << 16);
      p.y = (unsigned)f2b(kv.z) | ((unsigned)f2b(kv.w) << 16);
      *(uint2*)&K[row * 256 + (d4 ^ ((row & 7) << 3))] = p;
    }
    bar_lgkm();                          // BAR1: K visible; staging loads stay in flight

    // ---- logits + K^T (via identity MFMA) ----
    f32x4_t as_ = zero4;
    f32x4_t avT[2][4];
    #pragma unroll
    for (int kk = 0; kk < 8; ++kk){
      int colk = kk * 32 + 8 * h;
      bf16x8_t A0 = *(const bf16x8_t*)&K[c * 256 + (colk ^ ((c & 7) << 3))];
      bf16x8_t A1 = *(const bf16x8_t*)&K[(c + 16) * 256 + (colk ^ ((c & 7) << 3))];
      as_ = MFMA16(mt ? A1 : A0, qf[kk], as_);
      if (kk == 2 * w){
        avT[0][0] = MFMA16(A0, bIe, zero4);  avT[0][1] = MFMA16(A0, bIo, zero4);
        avT[1][0] = MFMA16(A1, bIe, zero4);  avT[1][1] = MFMA16(A1, bIo, zero4);
      }
      if (kk == 2 * w + 1){
        avT[0][2] = MFMA16(A0, bIe, zero4);  avT[0][3] = MFMA16(A0, bIo, zero4);
        avT[1][2] = MFMA16(A1, bIe, zero4);  avT[1][3] = MFMA16(A1, bIo, zero4);
      }
    }
    // vT[e][t] <- K^T (each wave owns e-range 64w..64w+63)
    #pragma unroll
    for (int m = 0; m < 2; ++m)
      #pragma unroll
      for (int nt = 0; nt < 4; ++nt){
        int e = 64 * w + 16 * nt + c;
        int t0 = 16 * m + 4 * h;
        uint2 p;
        p.x = (unsigned)f2b(avT[m][nt][0]) | ((unsigned)f2b(avT[m][nt][1]) << 16);
        p.y = (unsigned)f2b(avT[m][nt][2]) | ((unsigned)f2b(avT[m][nt][3]) << 16);
        *(uint2*)&vT[e * 32 + (t0 ^ ((e & 1) << 3))] = p;
      }

    // ---- softmax (fixed-max): P = exp(logit - slope*games_ago), masked -> 0 ----
    {
      float e_[4]; float qs_ = 0.f;
      #pragma unroll
      for (int i = 0; i < 4; ++i){
        int s = s0 + 16 * mt + 4 * h + i;
        float ga = (float)(n_real - 1 - s);
        bool valid = (s < n_real);
        float v = valid ? __expf(as_[i] - slope0 * ga) : 0.f;
        e_[i] = v; qs_ += v;
      }
      float r = qs_ + __shfl_xor(qs_, 16); r += __shfl_xor(r, 32);
      if (l < 16) atomicAdd(&denl[16 * qt + c], r);
      int q = 16 * qt + c;
      int t0 = 16 * mt + 4 * h;
      uint2 p;
      p.x = (unsigned)f2b(e_[0]) | ((unsigned)f2b(e_[1]) << 16);
      p.y = (unsigned)f2b(e_[2]) | ((unsigned)f2b(e_[3]) << 16);
      *(uint2*)&Pl[q * 32 + (t0 ^ ((q & 1) << 3))] = p;
    }
    bar_lgkm();                          // BAR2: vT/Pl visible

    // ---- PV over raw keys: ao[q][e] += P[q][t] * K[t][e] ----
    {
      bf16x8_t Ap0 = *(const bf16x8_t*)&Pl[c * 32 + ((8 * h) ^ ((c & 1) << 3))];
      bf16x8_t Ap1 = *(const bf16x8_t*)&Pl[(16 + c) * 32 + ((8 * h) ^ ((c & 1) << 3))];
      #pragma unroll
      for (int nt = 0; nt < 4; ++nt){
        int e = 64 * w + 16 * nt + c;
        bf16x8_t Bv = *(const bf16x8_t*)&vT[e * 32 + ((8 * h) ^ ((e & 1) << 3))];
        ao[0][nt] = MFMA16(Ap0, Bv, ao[0][nt]);
        ao[1][nt] = MFMA16(Ap1, Bv, ao[1][nt]);
      }
    }
  }

  // ---- accumulate partial numerators / denominators (last BAR2 ordered denl) ----
  #pragma unroll
  for (int q2 = 0; q2 < 2; ++q2)
    #pragma unroll
    for (int nt = 0; nt < 4; ++nt){
      int e = 64 * w + 16 * nt + c;
      #pragma unroll
      for (int i = 0; i < 4; ++i){
        int q = 16 * q2 + 4 * h + i;
        atomicAdd(&acc[((size_t)b * 32 + q) * 256 + e], ao[q2][nt][i]);
      }
    }
  if (tid < 32) atomicAdd(&deng[b * 32 + tid], denl[tid]);
}

// ---------------- epilogue (IN-PLACE on d_out): out[row][e'] = sum_d (out[row][d]/den[row]) * value_w[e'][d] ----------------
// Each block owns rows r0..r0+63 exclusively: reads them into LDS, barriers, writes them back.
__global__ __launch_bounds__(256) void vproj_norm(
    const float* __restrict__ deng, const unsigned short* __restrict__ wvb,
    float* __restrict__ out){
  __shared__ unsigned short at[64 * 256];
  __shared__ float dl[64];
  int tid = threadIdx.x, w = tid >> 6, l = tid & 63, h = l >> 4, c = l & 15;
  size_t r0 = (size_t)blockIdx.x * 64;
  if (tid < 64) dl[tid] = 1.f / deng[r0 + tid];
  __syncthreads();
  #pragma unroll
  for (int j = 0; j < 16; ++j){
    int idx = j * 256 + tid;
    int row = idx >> 6, c4 = (idx & 63) * 4;
    f32x4_t v = *(const f32x4_t*)(out + (r0 + row) * 256 + c4);
    float iv = dl[row];
    uint2 p;
    p.x = (unsigned)f2b(v[0] * iv) | ((unsigned)f2b(v[1] * iv) << 16);
    p.y = (unsigned)f2b(v[2] * iv) | ((unsigned)f2b(v[3] * iv) << 16);
    *(uint2*)&at[row * 256 + (c4 ^ ((row & 7) << 3))] = p;
  }
  __syncthreads();
  f32x4_t zero4 = {0.f, 0.f, 0.f, 0.f};
  f32x4_t a2[4][4];
  #pragma unroll
  for (int m = 0; m < 4; ++m)
    #pragma unroll
    for (int nt = 0; nt < 4; ++nt) a2[m][nt] = zero4;
  #pragma unroll
  for (int kk = 0; kk < 8; ++kk){
    bf16x8_t A[4];
    #pragma unroll
    for (int m = 0; m < 4; ++m){
      int row = c + 16 * m;
      A[m] = *(const bf16x8_t*)&at[row * 256 + ((kk * 32 + 8 * h) ^ ((row & 7) << 3))];
    }
    #pragma unroll
    for (int nt = 0; nt < 4; ++nt){
      int ep = 64 * w + 16 * nt + c;
      bf16x8_t Bv = *(const bf16x8_t*)(wvb + (size_t)ep * 256 + kk * 32 + 8 * h);
      #pragma unroll
      for (int m = 0; m < 4; ++m) a2[m][nt] = MFMA16(A[m], Bv, a2[m][nt]);
    }
  }
  #pragma unroll
  for (int m = 0; m < 4; ++m)
    #pragma unroll
    for (int nt = 0; nt < 4; ++nt)
      #pragma unroll
      for (int i = 0; i < 4; ++i){
        size_t row = r0 + 16 * m + 4 * h + i;
        int ep = 64 * w + 16 * nt + c;
        out[row * 256 + ep] = a2[m][nt][i];
      }
}

extern "C" void kernel_launch(void* const* d_in, const int* in_sizes, int n_in,
                              void* d_out, int out_size, void* d_ws, size_t ws_size,
                              hipStream_t stream){
  const float* keys    = (const float*)d_in[0];
  const int*   mask    = (const int*)d_in[1];
  const float* context = (const float*)d_in[2];
  const float* queries = (const float*)d_in[3];
  const float* key_w   = (const float*)d_in[4];
  const float* value_w = (const float*)d_in[5];
  const float* logt    = (const float*)d_in[6];
  const float* cond_w  = (const float*)d_in[7];
  const float* cond_b  = (const float*)d_in[8];
  float* out = (float*)d_out;

  unsigned short* wkt = (unsigned short*)d_ws;           // 65536 bf16
  unsigned short* wvb = wkt + 65536;                     // 65536 bf16
  unsigned short* qs  = wvb + 65536;                     // 16384*256 bf16
  unsigned short* qkp = qs + (size_t)16384 * 256;        // 16384*256 bf16
  float* deng = (float*)(qkp + (size_t)16384 * 256);     // 16384 f32
  int*   nreal = (int*)(deng + 16384);                   // 512 int

  hipLaunchKernelGGL(prep_w,   dim3(256), dim3(256), 0, stream, key_w, value_w, wkt, wvb);
  hipLaunchKernelGGL(nreal_k,  dim3(512), dim3(64),  0, stream, mask, nreal);
  hipLaunchKernelGGL(calc_qs,  dim3(256), dim3(256), 0, stream, context, queries, logt, cond_w, cond_b, qs);
  hipLaunchKernelGGL(calc_qkp, dim3(256), dim3(256), 0, stream, qs, wkt, qkp);
  hipLaunchKernelGGL(zero_k,   dim3(4096), dim3(256), 0, stream, (float4*)out, (float4*)deng);
  hipLaunchKernelGGL(attn_part, dim3(1024), dim3(256), 0, stream, keys, nreal, qkp, out, deng);
  hipLaunchKernelGGL(vproj_norm, dim3(256), dim3(256), 0, stream, deng, wvb, out);
}